// Round 7
// baseline (527.197 us; speedup 1.0000x reference)
//
#include <hip/hip_runtime.h>
#include <hip/hip_bf16.h>

#define D_MODEL 1024
#define F_DIM   2048
#define NE      8
#define NTOK    8192
#define MAXT    72
#define HBLK    32          // histogram/scatter blocks (256 tokens each)

typedef __attribute__((ext_vector_type(8))) short bf16x8;
typedef __attribute__((ext_vector_type(4))) float f32x4;

__device__ __forceinline__ unsigned short f2b(float f) {
    unsigned int u = __float_as_uint(f);
    u += 0x7FFFu + ((u >> 16) & 1u);          // RNE
    return (unsigned short)(u >> 16);
}
__device__ __forceinline__ unsigned int pack2(float a, float b) {
    return (unsigned int)f2b(a) | ((unsigned int)f2b(b) << 16);
}
__device__ __forceinline__ void async16(const void* g, void* l) {
    __builtin_amdgcn_global_load_lds((const __attribute__((address_space(1))) void*)g,
                                     (__attribute__((address_space(3))) void*)l, 16, 0, 0);
}

// ---- ternary quant, wave-per-row: whole row in one wave's registers ------------
template <int K>
__device__ __forceinline__ void quant_wave(const float* __restrict__ W,
                                           unsigned short* __restrict__ Q,
                                           int row) {
    constexpr int PV = K / 256;              // float4 per lane
    const int lane = threadIdx.x & 63;
    const float4* Wv = (const float4*)(W + (size_t)row * K);
    float4 v[PV];
#pragma unroll
    for (int i = 0; i < PV; i++) v[i] = Wv[lane + 64 * i];
    float s = 0.f;
#pragma unroll
    for (int i = 0; i < PV; i++)
        s += fabsf(v[i].x) + fabsf(v[i].y) + fabsf(v[i].z) + fabsf(v[i].w);
#pragma unroll
    for (int o = 32; o > 0; o >>= 1) s += __shfl_down(s, o);
    s = __shfl(s, 0);
    const float scale = fmaxf(s * (1.0f / K), 1e-5f);
    const float inv = 1.0f / scale;
    unsigned int* Qu = (unsigned int*)(Q + (size_t)row * K);
#pragma unroll
    for (int i = 0; i < PV; i++) {
        float q0 = fminf(1.f, fmaxf(-1.f, rintf(v[i].x * inv))) * scale;
        float q1 = fminf(1.f, fmaxf(-1.f, rintf(v[i].y * inv))) * scale;
        float q2 = fminf(1.f, fmaxf(-1.f, rintf(v[i].z * inv))) * scale;
        float q3 = fminf(1.f, fmaxf(-1.f, rintf(v[i].w * inv))) * scale;
        Qu[2 * (lane + 64 * i)]     = pack2(q0, q1);
        Qu[2 * (lane + 64 * i) + 1] = pack2(q2, q3);
    }
}

// -------- fused LayerNorm + router body: one wave per token, no atomics ---------
__device__ __forceinline__ void ln_dev(const float* __restrict__ x,
                                       const float* __restrict__ gamma,
                                       const float* __restrict__ beta,
                                       const float* __restrict__ rw,
                                       unsigned short* __restrict__ h,
                                       int* __restrict__ top_idx,
                                       float* __restrict__ top_prob,
                                       int blk) {
    const int lane = threadIdx.x & 63;
    const size_t tok = (size_t)blk * 4 + (threadIdx.x >> 6);

    const float4* xr = (const float4*)(x + tok * D_MODEL);
    float4 xv[4];
#pragma unroll
    for (int i = 0; i < 4; i++) xv[i] = xr[lane + 64 * i];
    float s = 0.f, q = 0.f;
#pragma unroll
    for (int i = 0; i < 4; i++) {
        s += xv[i].x + xv[i].y + xv[i].z + xv[i].w;
        q += xv[i].x * xv[i].x + xv[i].y * xv[i].y + xv[i].z * xv[i].z + xv[i].w * xv[i].w;
    }
#pragma unroll
    for (int o = 32; o > 0; o >>= 1) { s += __shfl_down(s, o); q += __shfl_down(q, o); }
    s = __shfl(s, 0); q = __shfl(q, 0);
    const float mean = s * (1.0f / D_MODEL);
    const float rstd = rsqrtf(q * (1.0f / D_MODEL) - mean * mean + 1e-5f);

    float4 hv[4];
    unsigned int* hr = (unsigned int*)(h + tok * D_MODEL);
#pragma unroll
    for (int i = 0; i < 4; i++) {
        const float4 g  = ((const float4*)gamma)[lane + 64 * i];
        const float4 bt = ((const float4*)beta)[lane + 64 * i];
        hv[i].x = (xv[i].x - mean) * rstd * g.x + bt.x;
        hv[i].y = (xv[i].y - mean) * rstd * g.y + bt.y;
        hv[i].z = (xv[i].z - mean) * rstd * g.z + bt.z;
        hv[i].w = (xv[i].w - mean) * rstd * g.w + bt.w;
        hr[2 * (lane + 64 * i)]     = pack2(hv[i].x, hv[i].y);
        hr[2 * (lane + 64 * i) + 1] = pack2(hv[i].z, hv[i].w);
    }

    float acc[NE];
#pragma unroll
    for (int e = 0; e < NE; e++) {
        const float4* rr = (const float4*)(rw + e * D_MODEL);
        float a = 0.f;
#pragma unroll
        for (int i = 0; i < 4; i++) {
            const float4 r = rr[lane + 64 * i];
            a += hv[i].x * r.x + hv[i].y * r.y + hv[i].z * r.z + hv[i].w * r.w;
        }
        acc[e] = a;
    }
#pragma unroll
    for (int e = 0; e < NE; e++) {
#pragma unroll
        for (int o = 32; o > 0; o >>= 1) acc[e] += __shfl_down(acc[e], o);
    }
    if (lane == 0) {
        float m = acc[0]; int bi = 0;
#pragma unroll
        for (int e = 1; e < NE; e++) { if (acc[e] > m) { m = acc[e]; bi = e; } }
        float se = 0.f;
#pragma unroll
        for (int e = 0; e < NE; e++) se += __expf(acc[e] - m);
        top_idx[tok]  = bi;
        top_prob[tok] = 1.0f / se;
    }
}

// ---- single fused pre-pass: all weight quants (wave-per-row) + LN/router -------
// [0,512) sw1 | [512,768) sw2 | [768,4864) ew1 | [4864,6912) ew2 | [6912,8960) ln
__global__ __launch_bounds__(256) void fused_pre(const float* __restrict__ sw1,
                                                 const float* __restrict__ sw2,
                                                 const float* __restrict__ ew1,
                                                 const float* __restrict__ ew2,
                                                 unsigned short* __restrict__ sw1q,
                                                 unsigned short* __restrict__ sw2q,
                                                 unsigned short* __restrict__ ew1q,
                                                 unsigned short* __restrict__ ew2q,
                                                 const float* __restrict__ x,
                                                 const float* __restrict__ gamma,
                                                 const float* __restrict__ beta,
                                                 const float* __restrict__ rw,
                                                 unsigned short* __restrict__ h,
                                                 int* __restrict__ top_idx,
                                                 float* __restrict__ top_prob) {
    const int b = blockIdx.x;
    const int w = threadIdx.x >> 6;
    if (b < 512)        quant_wave<1024>(sw1, sw1q, b * 4 + w);
    else if (b < 768)   quant_wave<2048>(sw2, sw2q, (b - 512) * 4 + w);
    else if (b < 4864)  quant_wave<1024>(ew1, ew1q, (b - 768) * 4 + w);
    else if (b < 6912)  quant_wave<2048>(ew2, ew2q, (b - 4864) * 4 + w);
    else                ln_dev(x, gamma, beta, rw, h, top_idx, top_prob, b - 6912);
}

// ------- routing plan: per-block LDS histogram -> parallel scan -> scatter -------
__global__ __launch_bounds__(256) void hist_kernel(const int* __restrict__ top_idx,
                                                   int* __restrict__ blockhist) {
    __shared__ int lh[NE];
    if (threadIdx.x < NE) lh[threadIdx.x] = 0;
    __syncthreads();
    const int t = blockIdx.x * 256 + threadIdx.x;
    atomicAdd(&lh[top_idx[t]], 1);
    __syncthreads();
    if (threadIdx.x < NE) blockhist[blockIdx.x * NE + threadIdx.x] = lh[threadIdx.x];
}

__global__ __launch_bounds__(256) void scan_plan(const int* __restrict__ blockhist,
                                                 int* __restrict__ base,
                                                 int4* __restrict__ tilemap,
                                                 int* __restrict__ tok_perm) {
    __shared__ int sh[HBLK * NE];
    __shared__ int counts[NE];
    __shared__ int offsets[NE];
    __shared__ int tstart[NE + 1];
    const int tid = threadIdx.x;
    sh[tid] = blockhist[tid];
    __syncthreads();
    if (tid < NE) {
        int c = 0;
#pragma unroll
        for (int b = 0; b < HBLK; b++) c += sh[b * NE + tid];
        counts[tid] = c;
    }
    __syncthreads();
    if (tid == 0) {
        int off = 0, slot = 0;
#pragma unroll
        for (int e = 0; e < NE; e++) {
            offsets[e] = off;
            tstart[e] = slot;
            slot += (counts[e] + 127) >> 7;
            off += counts[e];
        }
        tstart[NE] = slot;
    }
    __syncthreads();
    if (tid < MAXT) {
        int4 t; t.x = 0; t.y = 0; t.z = 0; t.w = 0;
#pragma unroll
        for (int e = 0; e < NE; e++) {
            if (tid >= tstart[e] && tid < tstart[e + 1]) {
                const int k = (tid - tstart[e]) << 7;
                t.x = e; t.y = offsets[e] + k; t.z = min(128, counts[e] - k);
            }
        }
        tilemap[tid] = t;
    }
    {
        const int b = tid >> 3, e = tid & 7;
        int r = offsets[e];
        for (int bb = 0; bb < b; bb++) r += sh[bb * NE + e];
        base[b * NE + e] = r;
    }
    if (tid < 128) tok_perm[NTOK + tid] = 0;   // pad rows for gather-tile A loads
}

__global__ __launch_bounds__(256) void scatter_tokens(const int* __restrict__ top_idx,
                                                      const float* __restrict__ top_prob,
                                                      const int* __restrict__ base,
                                                      int* __restrict__ tok_perm,
                                                      float* __restrict__ probg) {
    __shared__ int cur[NE];
    if (threadIdx.x < NE) cur[threadIdx.x] = base[blockIdx.x * NE + threadIdx.x];
    __syncthreads();
    const int t = blockIdx.x * 256 + threadIdx.x;
    const int e = top_idx[t];
    const int pos = atomicAdd(&cur[e], 1);     // LDS atomic — block-local
    tok_perm[pos] = t;
    probg[pos] = top_prob[t];
}

// ------------- BK=64, XOR-swizzled LDS, bf16 NT GEMM: C = A * B^T ----------------
// MODE 0: merged G1 — y<64: shared (A=h, B=sw1q, C=h1s); else routed (gather, ew1q, h1r)
// MODE 1: merged G2 — y<64: shared (A=h1s rows, B=sw2q): out[row] += v (HW f32 atomic)
//                     else : routed (A=h1r slots, B=ew2q[e]): out[tok_perm[row]] += p*v
//         out is zeroed by a leading hipMemsetAsync, so add-order is irrelevant.
template <int MODE>
__global__ __launch_bounds__(256) void gemm64(const unsigned short* __restrict__ A,
                                              const unsigned short* __restrict__ A2,
                                              const unsigned short* __restrict__ Bmain,
                                              const unsigned short* __restrict__ Bexp,
                                              unsigned short* __restrict__ C1s,
                                              unsigned short* __restrict__ C1r,
                                              float* __restrict__ Out,
                                              const int4* __restrict__ tilemap,
                                              const int* __restrict__ tok_perm,
                                              const float* __restrict__ probg) {
    constexpr int N = (MODE == 0) ? F_DIM : D_MODEL;
    constexpr int K = (MODE == 0) ? D_MODEL : F_DIM;
    constexpr unsigned GX = N / 128;                      // 16 or 8
    const unsigned flat = blockIdx.y * GX + blockIdx.x;
    const unsigned nwg  = gridDim.y * GX;                 // 2176 / 1088, both %8==0
    const unsigned swz  = (flat & 7u) * (nwg >> 3) + (flat >> 3);
    const unsigned bx   = swz & (GX - 1u);
    const unsigned by   = swz / GX;

    int m0, rowsValid;
    const unsigned short* B;
    const unsigned short* Asrc = A;
    unsigned short* Cb = nullptr;
    bool routed = false;
    if (by < 64) {
        m0 = by * 128; rowsValid = 128; B = Bmain;
        if (MODE == 0) Cb = C1s;
    } else {
        int4 tm = tilemap[by - 64];
        if (tm.z == 0) return;
        m0 = tm.y; rowsValid = tm.z;
        B = Bexp + (size_t)tm.x * F_DIM * D_MODEL;
        routed = true;
        if (MODE == 0) Cb = C1r;
        else           Asrc = A2;
    }
    const int n0 = bx * 128;

    __shared__ unsigned short As[128 * 64];   // 16 KB
    __shared__ unsigned short Bs[128 * 64];   // 16 KB

    const int tid = threadIdx.x;
    const int lane = tid & 63;
    const int w = tid >> 6;
    const int wm = w >> 1, wn = w & 1;

    f32x4 acc[4][4];
#pragma unroll
    for (int i = 0; i < 4; i++)
#pragma unroll
        for (int j = 0; j < 4; j++) acc[i][j] = (f32x4){0.f, 0.f, 0.f, 0.f};

    const int sRow = lane >> 3;
    const int sCol = ((lane & 7) ^ sRow) * 8;
    const unsigned short* aP[4];
    const unsigned short* bP[4];
#pragma unroll
    for (int qq = 0; qq < 4; qq++) {
        const int ra = w * 32 + qq * 8 + sRow;
        size_t arow;
        if (MODE == 0) arow = routed ? (size_t)tok_perm[m0 + ra] : (size_t)(m0 + ra);
        else           arow = (size_t)(m0 + ra);
        aP[qq] = Asrc + arow * (size_t)K + sCol;
        bP[qq] = B + (size_t)(n0 + ra) * K + sCol;
    }
    unsigned short* aL = As + w * 2048;
    unsigned short* bL = Bs + w * 2048;

    const int fr = lane & 15, fq = lane >> 4;
    const bf16x8* Ar = (const bf16x8*)As;
    const bf16x8* Br = (const bf16x8*)Bs;

    for (int k0 = 0; k0 < K; k0 += 64) {
#pragma unroll
        for (int qq = 0; qq < 4; qq++) async16(aP[qq] + k0, aL + qq * 512);
#pragma unroll
        for (int qq = 0; qq < 4; qq++) async16(bP[qq] + k0, bL + qq * 512);
        __syncthreads();
#pragma unroll
        for (int kc = 0; kc < 2; kc++) {
            bf16x8 af[4], bfr[4];
#pragma unroll
            for (int i = 0; i < 4; i++) {
                const int row = wm * 64 + i * 16 + fr;
                af[i] = Ar[row * 8 + (((kc << 2) + fq) ^ (fr & 7))];
            }
#pragma unroll
            for (int j = 0; j < 4; j++) {
                const int row = wn * 64 + j * 16 + fr;
                bfr[j] = Br[row * 8 + (((kc << 2) + fq) ^ (fr & 7))];
            }
#pragma unroll
            for (int i = 0; i < 4; i++)
#pragma unroll
                for (int j = 0; j < 4; j++)
                    acc[i][j] = __builtin_amdgcn_mfma_f32_16x16x32_bf16(af[i], bfr[j], acc[i][j], 0, 0, 0);
        }
        __syncthreads();
    }

    // epilogue: C/D layout col=lane&15, row=quad*4+reg (m89-verified)
#pragma unroll
    for (int i = 0; i < 4; i++) {
        const int rb = wm * 64 + i * 16 + fq * 4;
#pragma unroll
        for (int t = 0; t < 4; t++) {
            const int r = rb + t;
            if (r < rowsValid) {
#pragma unroll
                for (int j = 0; j < 4; j++) {
                    const int c = n0 + wn * 64 + j * 16 + fr;
                    float v = acc[i][j][t];
                    if (MODE == 0) {
                        const float den = 1.0f + __expf(-v);
                        v = v * __builtin_amdgcn_rcpf(den);   // fast silu
                        Cb[(size_t)(m0 + r) * N + c] = f2b(v);
                    } else {
                        if (routed) {
                            const int tokr = tok_perm[m0 + r];
                            unsafeAtomicAdd(Out + (size_t)tokr * N + c, probg[m0 + r] * v);
                        } else {
                            unsafeAtomicAdd(Out + (size_t)(m0 + r) * N + c, v);
                        }
                    }
                }
            }
        }
    }
}

// ---------------- launch ---------------------------------------------------------
extern "C" void kernel_launch(void* const* d_in, const int* in_sizes, int n_in,
                              void* d_out, int out_size, void* d_ws, size_t ws_size,
                              hipStream_t stream) {
    const float* x   = (const float*)d_in[0];
    const float* sw1 = (const float*)d_in[1];
    const float* sw2 = (const float*)d_in[2];
    const float* ew1 = (const float*)d_in[3];
    const float* ew2 = (const float*)d_in[4];
    const float* rw  = (const float*)d_in[5];
    const float* gam = (const float*)d_in[6];
    const float* bet = (const float*)d_in[7];
    float* out = (float*)d_out;

    char* ws = (char*)d_ws;
    const size_t H_OFF    = 0;
    const size_t SW1Q_OFF = H_OFF + (size_t)NTOK * D_MODEL * 2;
    const size_t SW2Q_OFF = SW1Q_OFF + (size_t)F_DIM * D_MODEL * 2;
    const size_t EW1Q_OFF = SW2Q_OFF + (size_t)D_MODEL * F_DIM * 2;
    const size_t EW2Q_OFF = EW1Q_OFF + (size_t)NE * F_DIM * D_MODEL * 2;
    const size_t H1S_OFF  = EW2Q_OFF + (size_t)NE * D_MODEL * F_DIM * 2;
    const size_t H1R_OFF  = H1S_OFF + (size_t)NTOK * F_DIM * 2;
    const size_t PERM_OFF = H1R_OFF + (size_t)(NTOK + 128) * F_DIM * 2;
    const size_t PROBG_OFF = PERM_OFF + (NTOK + 128) * 4;
    const size_t IDX_OFF   = PROBG_OFF + (NTOK + 128) * 4;
    const size_t PROB_OFF  = IDX_OFF + NTOK * 4;
    const size_t BH_OFF    = PROB_OFF + NTOK * 4;
    const size_t BASE_OFF  = BH_OFF + HBLK * NE * 4;
    const size_t TILE_OFF  = BASE_OFF + HBLK * NE * 4;

    unsigned short* h     = (unsigned short*)(ws + H_OFF);
    unsigned short* sw1q  = (unsigned short*)(ws + SW1Q_OFF);
    unsigned short* sw2q  = (unsigned short*)(ws + SW2Q_OFF);
    unsigned short* ew1q  = (unsigned short*)(ws + EW1Q_OFF);
    unsigned short* ew2q  = (unsigned short*)(ws + EW2Q_OFF);
    unsigned short* h1s   = (unsigned short*)(ws + H1S_OFF);
    unsigned short* h1r   = (unsigned short*)(ws + H1R_OFF);
    int*   tok_perm = (int*)(ws + PERM_OFF);
    float* probg    = (float*)(ws + PROBG_OFF);
    int*   idx      = (int*)(ws + IDX_OFF);
    float* prob     = (float*)(ws + PROB_OFF);
    int*   blockhist = (int*)(ws + BH_OFF);
    int*   base      = (int*)(ws + BASE_OFF);
    int4*  tilemap   = (int4*)(ws + TILE_OFF);

    // 0) zero the output (atomic-accumulated by merged G2); graph-capture-safe
    hipMemsetAsync(out, 0, (size_t)NTOK * D_MODEL * sizeof(float), stream);

    // 1) all weight quants (wave-per-row) + LN/router in one launch
    fused_pre<<<8960, 256, 0, stream>>>(sw1, sw2, ew1, ew2, sw1q, sw2q, ew1q, ew2q,
                                        x, gam, bet, rw, h, idx, prob);

    // 2) routing plan
    hist_kernel<<<HBLK, 256, 0, stream>>>(idx, blockhist);
    scan_plan<<<1, 256, 0, stream>>>(blockhist, base, tilemap, tok_perm);
    scatter_tokens<<<HBLK, 256, 0, stream>>>(idx, prob, base, tok_perm, probg);

    // 3) G1 merged: h1s = silu(h @ sw1^T) [y<64]; h1r = silu(h[perm] @ ew1[e]^T)
    gemm64<0><<<dim3(F_DIM / 128, 64 + MAXT), 256, 0, stream>>>(
        h, nullptr, sw1q, ew1q, h1s, h1r, nullptr, tilemap, tok_perm, nullptr);

    // 4) G2 merged one launch: shared tiles + routed slot tiles, HW f32 atomic adds
    gemm64<1><<<dim3(D_MODEL / 128, 64 + MAXT), 256, 0, stream>>>(
        h1s, h1r, sw2q, ew2q, nullptr, nullptr, out, tilemap, tok_perm, probg);
}

// Round 8
// 410.356 us; speedup vs baseline: 1.2847x; 1.2847x over previous
//
#include <hip/hip_runtime.h>
#include <hip/hip_bf16.h>

#define D_MODEL 1024
#define F_DIM   2048
#define NE      8
#define NTOK    8192
#define MAXT    72
#define HBLK    32          // histogram/scatter blocks (256 tokens each)

typedef __attribute__((ext_vector_type(8))) short bf16x8;
typedef __attribute__((ext_vector_type(4))) float f32x4;

__device__ __forceinline__ unsigned short f2b(float f) {
    unsigned int u = __float_as_uint(f);
    u += 0x7FFFu + ((u >> 16) & 1u);          // RNE
    return (unsigned short)(u >> 16);
}
__device__ __forceinline__ unsigned int pack2(float a, float b) {
    return (unsigned int)f2b(a) | ((unsigned int)f2b(b) << 16);
}
__device__ __forceinline__ void async16(const void* g, void* l) {
    __builtin_amdgcn_global_load_lds((const __attribute__((address_space(1))) void*)g,
                                     (__attribute__((address_space(3))) void*)l, 16, 0, 0);
}

// ---- ternary quant, wave-per-row: whole row in one wave's registers ------------
template <int K>
__device__ __forceinline__ void quant_wave(const float* __restrict__ W,
                                           unsigned short* __restrict__ Q,
                                           int row) {
    constexpr int PV = K / 256;              // float4 per lane
    const int lane = threadIdx.x & 63;
    const float4* Wv = (const float4*)(W + (size_t)row * K);
    float4 v[PV];
#pragma unroll
    for (int i = 0; i < PV; i++) v[i] = Wv[lane + 64 * i];
    float s = 0.f;
#pragma unroll
    for (int i = 0; i < PV; i++)
        s += fabsf(v[i].x) + fabsf(v[i].y) + fabsf(v[i].z) + fabsf(v[i].w);
#pragma unroll
    for (int o = 32; o > 0; o >>= 1) s += __shfl_down(s, o);
    s = __shfl(s, 0);
    const float scale = fmaxf(s * (1.0f / K), 1e-5f);
    const float inv = 1.0f / scale;
    unsigned int* Qu = (unsigned int*)(Q + (size_t)row * K);
#pragma unroll
    for (int i = 0; i < PV; i++) {
        float q0 = fminf(1.f, fmaxf(-1.f, rintf(v[i].x * inv))) * scale;
        float q1 = fminf(1.f, fmaxf(-1.f, rintf(v[i].y * inv))) * scale;
        float q2 = fminf(1.f, fmaxf(-1.f, rintf(v[i].z * inv))) * scale;
        float q3 = fminf(1.f, fmaxf(-1.f, rintf(v[i].w * inv))) * scale;
        Qu[2 * (lane + 64 * i)]     = pack2(q0, q1);
        Qu[2 * (lane + 64 * i) + 1] = pack2(q2, q3);
    }
}

// -------- fused LayerNorm + router body: one wave per token, no atomics ---------
__device__ __forceinline__ void ln_dev(const float* __restrict__ x,
                                       const float* __restrict__ gamma,
                                       const float* __restrict__ beta,
                                       const float* __restrict__ rw,
                                       unsigned short* __restrict__ h,
                                       int* __restrict__ top_idx,
                                       float* __restrict__ top_prob,
                                       int blk) {
    const int lane = threadIdx.x & 63;
    const size_t tok = (size_t)blk * 4 + (threadIdx.x >> 6);

    const float4* xr = (const float4*)(x + tok * D_MODEL);
    float4 xv[4];
#pragma unroll
    for (int i = 0; i < 4; i++) xv[i] = xr[lane + 64 * i];
    float s = 0.f, q = 0.f;
#pragma unroll
    for (int i = 0; i < 4; i++) {
        s += xv[i].x + xv[i].y + xv[i].z + xv[i].w;
        q += xv[i].x * xv[i].x + xv[i].y * xv[i].y + xv[i].z * xv[i].z + xv[i].w * xv[i].w;
    }
#pragma unroll
    for (int o = 32; o > 0; o >>= 1) { s += __shfl_down(s, o); q += __shfl_down(q, o); }
    s = __shfl(s, 0); q = __shfl(q, 0);
    const float mean = s * (1.0f / D_MODEL);
    const float rstd = rsqrtf(q * (1.0f / D_MODEL) - mean * mean + 1e-5f);

    float4 hv[4];
    unsigned int* hr = (unsigned int*)(h + tok * D_MODEL);
#pragma unroll
    for (int i = 0; i < 4; i++) {
        const float4 g  = ((const float4*)gamma)[lane + 64 * i];
        const float4 bt = ((const float4*)beta)[lane + 64 * i];
        hv[i].x = (xv[i].x - mean) * rstd * g.x + bt.x;
        hv[i].y = (xv[i].y - mean) * rstd * g.y + bt.y;
        hv[i].z = (xv[i].z - mean) * rstd * g.z + bt.z;
        hv[i].w = (xv[i].w - mean) * rstd * g.w + bt.w;
        hr[2 * (lane + 64 * i)]     = pack2(hv[i].x, hv[i].y);
        hr[2 * (lane + 64 * i) + 1] = pack2(hv[i].z, hv[i].w);
    }

    float acc[NE];
#pragma unroll
    for (int e = 0; e < NE; e++) {
        const float4* rr = (const float4*)(rw + e * D_MODEL);
        float a = 0.f;
#pragma unroll
        for (int i = 0; i < 4; i++) {
            const float4 r = rr[lane + 64 * i];
            a += hv[i].x * r.x + hv[i].y * r.y + hv[i].z * r.z + hv[i].w * r.w;
        }
        acc[e] = a;
    }
#pragma unroll
    for (int e = 0; e < NE; e++) {
#pragma unroll
        for (int o = 32; o > 0; o >>= 1) acc[e] += __shfl_down(acc[e], o);
    }
    if (lane == 0) {
        float m = acc[0]; int bi = 0;
#pragma unroll
        for (int e = 1; e < NE; e++) { if (acc[e] > m) { m = acc[e]; bi = e; } }
        float se = 0.f;
#pragma unroll
        for (int e = 0; e < NE; e++) se += __expf(acc[e] - m);
        top_idx[tok]  = bi;
        top_prob[tok] = 1.0f / se;
    }
}

// ---- single fused pre-pass: all weight quants (wave-per-row) + LN/router -------
// [0,512) sw1 | [512,768) sw2 | [768,4864) ew1 | [4864,6912) ew2 | [6912,8960) ln
__global__ __launch_bounds__(256) void fused_pre(const float* __restrict__ sw1,
                                                 const float* __restrict__ sw2,
                                                 const float* __restrict__ ew1,
                                                 const float* __restrict__ ew2,
                                                 unsigned short* __restrict__ sw1q,
                                                 unsigned short* __restrict__ sw2q,
                                                 unsigned short* __restrict__ ew1q,
                                                 unsigned short* __restrict__ ew2q,
                                                 const float* __restrict__ x,
                                                 const float* __restrict__ gamma,
                                                 const float* __restrict__ beta,
                                                 const float* __restrict__ rw,
                                                 unsigned short* __restrict__ h,
                                                 int* __restrict__ top_idx,
                                                 float* __restrict__ top_prob) {
    const int b = blockIdx.x;
    const int w = threadIdx.x >> 6;
    if (b < 512)        quant_wave<1024>(sw1, sw1q, b * 4 + w);
    else if (b < 768)   quant_wave<2048>(sw2, sw2q, (b - 512) * 4 + w);
    else if (b < 4864)  quant_wave<1024>(ew1, ew1q, (b - 768) * 4 + w);
    else if (b < 6912)  quant_wave<2048>(ew2, ew2q, (b - 4864) * 4 + w);
    else                ln_dev(x, gamma, beta, rw, h, top_idx, top_prob, b - 6912);
}

// ------- routing plan: per-block LDS histogram -> parallel scan -> scatter -------
__global__ __launch_bounds__(256) void hist_kernel(const int* __restrict__ top_idx,
                                                   int* __restrict__ blockhist) {
    __shared__ int lh[NE];
    if (threadIdx.x < NE) lh[threadIdx.x] = 0;
    __syncthreads();
    const int t = blockIdx.x * 256 + threadIdx.x;
    atomicAdd(&lh[top_idx[t]], 1);
    __syncthreads();
    if (threadIdx.x < NE) blockhist[blockIdx.x * NE + threadIdx.x] = lh[threadIdx.x];
}

__global__ __launch_bounds__(256) void scan_plan(const int* __restrict__ blockhist,
                                                 int* __restrict__ base,
                                                 int4* __restrict__ tilemap,
                                                 int* __restrict__ tok_perm) {
    __shared__ int sh[HBLK * NE];
    __shared__ int counts[NE];
    __shared__ int offsets[NE];
    __shared__ int tstart[NE + 1];
    const int tid = threadIdx.x;
    sh[tid] = blockhist[tid];
    __syncthreads();
    if (tid < NE) {
        int c = 0;
#pragma unroll
        for (int b = 0; b < HBLK; b++) c += sh[b * NE + tid];
        counts[tid] = c;
    }
    __syncthreads();
    if (tid == 0) {
        int off = 0, slot = 0;
#pragma unroll
        for (int e = 0; e < NE; e++) {
            offsets[e] = off;
            tstart[e] = slot;
            slot += (counts[e] + 127) >> 7;
            off += counts[e];
        }
        tstart[NE] = slot;
    }
    __syncthreads();
    if (tid < MAXT) {
        int4 t; t.x = 0; t.y = 0; t.z = 0; t.w = 0;
#pragma unroll
        for (int e = 0; e < NE; e++) {
            if (tid >= tstart[e] && tid < tstart[e + 1]) {
                const int k = (tid - tstart[e]) << 7;
                t.x = e; t.y = offsets[e] + k; t.z = min(128, counts[e] - k);
            }
        }
        tilemap[tid] = t;
    }
    {
        const int b = tid >> 3, e = tid & 7;
        int r = offsets[e];
        for (int bb = 0; bb < b; bb++) r += sh[bb * NE + e];
        base[b * NE + e] = r;
    }
    if (tid < 128) tok_perm[NTOK + tid] = 0;   // pad rows for gather-tile A loads
}

__global__ __launch_bounds__(256) void scatter_tokens(const int* __restrict__ top_idx,
                                                      const float* __restrict__ top_prob,
                                                      const int* __restrict__ base,
                                                      int* __restrict__ tok_perm,
                                                      float* __restrict__ probg) {
    __shared__ int cur[NE];
    if (threadIdx.x < NE) cur[threadIdx.x] = base[blockIdx.x * NE + threadIdx.x];
    __syncthreads();
    const int t = blockIdx.x * 256 + threadIdx.x;
    const int e = top_idx[t];
    const int pos = atomicAdd(&cur[e], 1);     // LDS atomic — block-local
    tok_perm[pos] = t;
    probg[pos] = top_prob[t];
}

// ------------- G1: BK=64, XOR-swizzled LDS, bf16 NT GEMM (r4-exact) --------------
// MODE 0 only: y<64: shared (A=h, B=sw1q, C=h1s); else routed (gather, ew1q, h1r)
template <int MODE>
__global__ __launch_bounds__(256) void gemm64(const unsigned short* __restrict__ A,
                                              const unsigned short* __restrict__ Bmain,
                                              const unsigned short* __restrict__ Bexp,
                                              unsigned short* __restrict__ C1s,
                                              unsigned short* __restrict__ C1r,
                                              float* __restrict__ Out,
                                              int N, int K,
                                              const int4* __restrict__ tilemap,
                                              const int* __restrict__ tok_perm,
                                              const float* __restrict__ probg) {
    constexpr unsigned GX = (MODE == 0) ? (F_DIM / 128) : (D_MODEL / 128);
    const unsigned flat = blockIdx.y * GX + blockIdx.x;
    const unsigned nwg  = gridDim.y * GX;
    const unsigned swz  = (flat & 7u) * (nwg >> 3) + (flat >> 3);
    const unsigned bx   = swz & (GX - 1u);
    const unsigned by   = swz / GX;

    int m0, rowsValid;
    const unsigned short* B;
    unsigned short* Cb = nullptr;
    bool gather = false;
    if (MODE == 0) {
        if (by < 64) {
            m0 = by * 128; rowsValid = 128; B = Bmain; Cb = C1s;
        } else {
            int4 tm = tilemap[by - 64];
            if (tm.z == 0) return;
            m0 = tm.y; rowsValid = tm.z;
            B = Bexp + (size_t)tm.x * F_DIM * D_MODEL;
            Cb = C1r; gather = true;
        }
    } else if (MODE == 1) {
        int4 tm = tilemap[by];
        if (tm.z == 0) return;
        m0 = tm.y; rowsValid = tm.z;
        B = Bmain + (size_t)tm.x * D_MODEL * F_DIM;
    } else {
        m0 = by * 128; rowsValid = 128; B = Bmain;
    }
    const int n0 = bx * 128;

    __shared__ unsigned short As[128 * 64];   // 16 KB
    __shared__ unsigned short Bs[128 * 64];   // 16 KB

    const int tid = threadIdx.x;
    const int lane = tid & 63;
    const int w = tid >> 6;
    const int wm = w >> 1, wn = w & 1;

    f32x4 acc[4][4];
#pragma unroll
    for (int i = 0; i < 4; i++)
#pragma unroll
        for (int j = 0; j < 4; j++) acc[i][j] = (f32x4){0.f, 0.f, 0.f, 0.f};

    const int sRow = lane >> 3;
    const int sCol = ((lane & 7) ^ sRow) * 8;
    const unsigned short* aP[4];
    const unsigned short* bP[4];
#pragma unroll
    for (int qq = 0; qq < 4; qq++) {
        const int ra = w * 32 + qq * 8 + sRow;
        size_t arow;
        if (MODE == 0) arow = gather ? (size_t)tok_perm[m0 + ra] : (size_t)(m0 + ra);
        else           arow = (size_t)(m0 + ra);
        aP[qq] = A + arow * (size_t)K + sCol;
        bP[qq] = B + (size_t)(n0 + ra) * K + sCol;
    }
    unsigned short* aL = As + w * 2048;
    unsigned short* bL = Bs + w * 2048;

    const int fr = lane & 15, fq = lane >> 4;
    const bf16x8* Ar = (const bf16x8*)As;
    const bf16x8* Br = (const bf16x8*)Bs;

    for (int k0 = 0; k0 < K; k0 += 64) {
#pragma unroll
        for (int qq = 0; qq < 4; qq++) async16(aP[qq] + k0, aL + qq * 512);
#pragma unroll
        for (int qq = 0; qq < 4; qq++) async16(bP[qq] + k0, bL + qq * 512);
        __syncthreads();
#pragma unroll
        for (int kc = 0; kc < 2; kc++) {
            bf16x8 af[4], bfr[4];
#pragma unroll
            for (int i = 0; i < 4; i++) {
                const int row = wm * 64 + i * 16 + fr;
                af[i] = Ar[row * 8 + (((kc << 2) + fq) ^ (fr & 7))];
            }
#pragma unroll
            for (int j = 0; j < 4; j++) {
                const int row = wn * 64 + j * 16 + fr;
                bfr[j] = Br[row * 8 + (((kc << 2) + fq) ^ (fr & 7))];
            }
#pragma unroll
            for (int i = 0; i < 4; i++)
#pragma unroll
                for (int j = 0; j < 4; j++)
                    acc[i][j] = __builtin_amdgcn_mfma_f32_16x16x32_bf16(af[i], bfr[j], acc[i][j], 0, 0, 0);
        }
        __syncthreads();
    }

#pragma unroll
    for (int i = 0; i < 4; i++) {
        const int rb = wm * 64 + i * 16 + fq * 4;
#pragma unroll
        for (int t = 0; t < 4; t++) {
            const int r = rb + t;
            if (r < rowsValid) {
#pragma unroll
                for (int j = 0; j < 4; j++) {
                    const int c = n0 + wn * 64 + j * 16 + fr;
                    float v = acc[i][j][t];
                    if (MODE == 0) {
                        const float den = 1.0f + __expf(-v);
                        v = v * __builtin_amdgcn_rcpf(den);   // fast silu
                        Cb[(size_t)(m0 + r) * N + c] = f2b(v);
                    } else if (MODE == 1) {
                        const int tokr = tok_perm[m0 + r];
                        Out[(size_t)tokr * N + c] = probg[m0 + r] * v;
                    } else {
                        float* o = Out + (size_t)(m0 + r) * N + c;
                        *o = *o + v;
                    }
                }
            }
        }
    }
}

// ------------- G2: 128x64 tile, BK=64 — fine grid to fix resident-block starvation
// ROUTED: A=h1r slot rows, B=ew2q[e]; Out[tok_perm[row]] = probg[row] * v (plain store)
// !ROUTED: A=h1s token rows, B=sw2q;  Out[row] += v (read-add, runs after routed)
// LDS = 16KB(A) + 8KB(B) = 24KB -> up to 6 blocks/CU; grids 1152/1024 (~4.5/CU).
template <bool ROUTED>
__global__ __launch_bounds__(256) void gemm_g2(const unsigned short* __restrict__ A,
                                               const unsigned short* __restrict__ Bmain,
                                               float* __restrict__ Out,
                                               const int4* __restrict__ tilemap,
                                               const int* __restrict__ tok_perm,
                                               const float* __restrict__ probg) {
    constexpr int N = D_MODEL, K = F_DIM;
    constexpr unsigned GX = N / 64;                       // 16
    const unsigned flat = blockIdx.y * GX + blockIdx.x;
    const unsigned nwg  = gridDim.y * GX;                 // 1152 / 1024, %8==0
    const unsigned swz  = (flat & 7u) * (nwg >> 3) + (flat >> 3);
    const unsigned bx   = swz & (GX - 1u);
    const unsigned by   = swz / GX;

    int m0, rowsValid;
    const unsigned short* B;
    if (ROUTED) {
        int4 tm = tilemap[by];
        if (tm.z == 0) return;
        m0 = tm.y; rowsValid = tm.z;
        B = Bmain + (size_t)tm.x * D_MODEL * F_DIM;       // ew2q[e]
    } else {
        m0 = by * 128; rowsValid = 128; B = Bmain;        // sw2q
    }
    const int n0 = bx * 64;

    __shared__ unsigned short As[128 * 64];   // 16 KB
    __shared__ unsigned short Bs[64 * 64];    //  8 KB

    const int tid = threadIdx.x;
    const int lane = tid & 63;
    const int w = tid >> 6;

    f32x4 acc[2][4];
#pragma unroll
    for (int i = 0; i < 2; i++)
#pragma unroll
        for (int j = 0; j < 4; j++) acc[i][j] = (f32x4){0.f, 0.f, 0.f, 0.f};

    const int sRow = lane >> 3;
    const int sCol = ((lane & 7) ^ sRow) * 8;
    const unsigned short* aP[4];
    const unsigned short* bP[2];
#pragma unroll
    for (int qq = 0; qq < 4; qq++) {
        const int ra = w * 32 + qq * 8 + sRow;
        aP[qq] = A + (size_t)(m0 + ra) * K + sCol;
    }
#pragma unroll
    for (int qq = 0; qq < 2; qq++) {
        const int rb = w * 16 + qq * 8 + sRow;
        bP[qq] = B + (size_t)(n0 + rb) * K + sCol;
    }
    unsigned short* aL = As + w * 2048;   // 32 rows * 64
    unsigned short* bL = Bs + w * 1024;   // 16 rows * 64

    const int fr = lane & 15, fq = lane >> 4;
    const bf16x8* Ar = (const bf16x8*)As;
    const bf16x8* Br = (const bf16x8*)Bs;

    for (int k0 = 0; k0 < K; k0 += 64) {
#pragma unroll
        for (int qq = 0; qq < 4; qq++) async16(aP[qq] + k0, aL + qq * 512);
#pragma unroll
        for (int qq = 0; qq < 2; qq++) async16(bP[qq] + k0, bL + qq * 512);
        __syncthreads();
#pragma unroll
        for (int kc = 0; kc < 2; kc++) {
            bf16x8 af[2], bfr[4];
#pragma unroll
            for (int i = 0; i < 2; i++) {
                const int row = w * 32 + i * 16 + fr;
                af[i] = Ar[row * 8 + (((kc << 2) + fq) ^ (fr & 7))];
            }
#pragma unroll
            for (int j = 0; j < 4; j++) {
                const int row = j * 16 + fr;
                bfr[j] = Br[row * 8 + (((kc << 2) + fq) ^ (fr & 7))];
            }
#pragma unroll
            for (int i = 0; i < 2; i++)
#pragma unroll
                for (int j = 0; j < 4; j++)
                    acc[i][j] = __builtin_amdgcn_mfma_f32_16x16x32_bf16(af[i], bfr[j], acc[i][j], 0, 0, 0);
        }
        __syncthreads();
    }

    // epilogue: wave w owns rows w*32..w*32+31, cols n0..n0+63
#pragma unroll
    for (int i = 0; i < 2; i++) {
        const int rb = w * 32 + i * 16 + fq * 4;
#pragma unroll
        for (int t = 0; t < 4; t++) {
            const int r = rb + t;
            if (r < rowsValid) {
#pragma unroll
                for (int j = 0; j < 4; j++) {
                    const int c = n0 + j * 16 + fr;
                    float v = acc[i][j][t];
                    if (ROUTED) {
                        const int tokr = tok_perm[m0 + r];
                        Out[(size_t)tokr * N + c] = probg[m0 + r] * v;
                    } else {
                        float* o = Out + (size_t)(m0 + r) * N + c;
                        *o = *o + v;
                    }
                }
            }
        }
    }
}

// ---------------- launch ---------------------------------------------------------
extern "C" void kernel_launch(void* const* d_in, const int* in_sizes, int n_in,
                              void* d_out, int out_size, void* d_ws, size_t ws_size,
                              hipStream_t stream) {
    const float* x   = (const float*)d_in[0];
    const float* sw1 = (const float*)d_in[1];
    const float* sw2 = (const float*)d_in[2];
    const float* ew1 = (const float*)d_in[3];
    const float* ew2 = (const float*)d_in[4];
    const float* rw  = (const float*)d_in[5];
    const float* gam = (const float*)d_in[6];
    const float* bet = (const float*)d_in[7];
    float* out = (float*)d_out;

    char* ws = (char*)d_ws;
    const size_t H_OFF    = 0;
    const size_t SW1Q_OFF = H_OFF + (size_t)NTOK * D_MODEL * 2;
    const size_t SW2Q_OFF = SW1Q_OFF + (size_t)F_DIM * D_MODEL * 2;
    const size_t EW1Q_OFF = SW2Q_OFF + (size_t)D_MODEL * F_DIM * 2;
    const size_t EW2Q_OFF = EW1Q_OFF + (size_t)NE * F_DIM * D_MODEL * 2;
    const size_t H1S_OFF  = EW2Q_OFF + (size_t)NE * D_MODEL * F_DIM * 2;
    const size_t H1R_OFF  = H1S_OFF + (size_t)NTOK * F_DIM * 2;
    const size_t PERM_OFF = H1R_OFF + (size_t)(NTOK + 128) * F_DIM * 2;
    const size_t PROBG_OFF = PERM_OFF + (NTOK + 128) * 4;
    const size_t IDX_OFF   = PROBG_OFF + (NTOK + 128) * 4;
    const size_t PROB_OFF  = IDX_OFF + NTOK * 4;
    const size_t BH_OFF    = PROB_OFF + NTOK * 4;
    const size_t BASE_OFF  = BH_OFF + HBLK * NE * 4;
    const size_t TILE_OFF  = BASE_OFF + HBLK * NE * 4;

    unsigned short* h     = (unsigned short*)(ws + H_OFF);
    unsigned short* sw1q  = (unsigned short*)(ws + SW1Q_OFF);
    unsigned short* sw2q  = (unsigned short*)(ws + SW2Q_OFF);
    unsigned short* ew1q  = (unsigned short*)(ws + EW1Q_OFF);
    unsigned short* ew2q  = (unsigned short*)(ws + EW2Q_OFF);
    unsigned short* h1s   = (unsigned short*)(ws + H1S_OFF);
    unsigned short* h1r   = (unsigned short*)(ws + H1R_OFF);
    int*   tok_perm = (int*)(ws + PERM_OFF);
    float* probg    = (float*)(ws + PROBG_OFF);
    int*   idx      = (int*)(ws + IDX_OFF);
    float* prob     = (float*)(ws + PROB_OFF);
    int*   blockhist = (int*)(ws + BH_OFF);
    int*   base      = (int*)(ws + BASE_OFF);
    int4*  tilemap   = (int4*)(ws + TILE_OFF);

    // 1) all weight quants (wave-per-row) + LN/router in one launch
    fused_pre<<<8960, 256, 0, stream>>>(sw1, sw2, ew1, ew2, sw1q, sw2q, ew1q, ew2q,
                                        x, gam, bet, rw, h, idx, prob);

    // 2) routing plan
    hist_kernel<<<HBLK, 256, 0, stream>>>(idx, blockhist);
    scan_plan<<<1, 256, 0, stream>>>(blockhist, base, tilemap, tok_perm);
    scatter_tokens<<<HBLK, 256, 0, stream>>>(idx, prob, base, tok_perm, probg);

    // 3) G1 merged: h1s = silu(h @ sw1^T) [y<64]; h1r = silu(h[perm] @ ew1[e]^T)
    gemm64<0><<<dim3(F_DIM / 128, 64 + MAXT), 256, 0, stream>>>(
        h, sw1q, ew1q, h1s, h1r, nullptr, F_DIM, D_MODEL, tilemap, tok_perm, nullptr);

    // 4) G2 fine-grid pair: routed plain-store first, shared read-add second
    gemm_g2<true><<<dim3(D_MODEL / 64, MAXT), 256, 0, stream>>>(
        h1r, ew2q, out, tilemap, tok_perm, probg);
    gemm_g2<false><<<dim3(D_MODEL / 64, NTOK / 128), 256, 0, stream>>>(
        h1s, sw2q, out, tilemap, tok_perm, probg);
}